// Round 10
// baseline (632.405 us; speedup 1.0000x reference)
//
#include <hip/hip_runtime.h>

// Voxelizer3D: out[f][z][y][x] = sum over masked atoms (all coords != 0) whose
// center cell is within Chebyshev distance 1 of (x,y,z), of feat[a][f].
// v10: single cooperative mega-kernel with HAND-ROLLED grid barrier (no
// cg::grid.sync -> no s_sleep backoff) and INTERLEAVED phase-C cell groups
// (grid-stride, kills the Gaussian-center load imbalance of v9).
// Fallback: r8's proven 4-dispatch pipeline.

constexpr int VOL   = 48;
constexpr int FEATD = 19;
constexpr int VOL3  = VOL * VOL * VOL;      // 110592
constexpr int CAP   = 128;                  // bucket capacity per cell
constexpr int OVCAP = 8192;                 // overflow list capacity (cold)
constexpr int SCB   = 256;
constexpr int ZK    = 4;                    // z outputs per conv thread
constexpr int NBLK  = 1024;                 // 4 blocks/CU * 256 CU
constexpr int NGRP  = VOL3 / 4;             // 27648 four-cell groups

__device__ __forceinline__ unsigned fkey(float f) {
    unsigned u = __float_as_uint(f);
    return (u & 0x80000000u) ? ~u : (u | 0x80000000u);
}
__device__ __forceinline__ float funkey(unsigned k) {
    unsigned u = (k & 0x80000000u) ? (k & 0x7fffffffu) : ~k;
    return __uint_as_float(u);
}

// ---- custom grid barrier: module globals (init 0 at load; cnt self-resets,
// gen grows monotonically across launches -> deterministic behavior) ----
__device__ unsigned g_cnt = 0;
__device__ unsigned g_gen = 0;

__device__ __forceinline__ void gbar(int nblk) {
    __threadfence();                 // release: my writes visible device-wide
    __syncthreads();
    if (threadIdx.x == 0) {
        unsigned g = atomicAdd(&g_gen, 0u);          // read gen BEFORE arrival
        if (atomicAdd(&g_cnt, 1u) == (unsigned)nblk - 1u) {
            atomicExch(&g_cnt, 0u);                  // reset BEFORE release
            atomicAdd(&g_gen, 1u);                   // release
        } else {
            while (atomicAdd(&g_gen, 0u) == g) {}    // active spin, no sleep
        }
    }
    __syncthreads();
    __threadfence();                 // acquire: invalidate stale caches
}

// ================= single-launch cooperative mega-kernel =================
__global__ __launch_bounds__(SCB, 4) void vox_mega(
        const float* __restrict__ xyz, const float* __restrict__ feat, int n,
        unsigned* __restrict__ pb, unsigned* __restrict__ counts,
        unsigned* __restrict__ ovf_cnt, unsigned* __restrict__ bucket,
        unsigned* __restrict__ ovf, float* __restrict__ center,
        float* __restrict__ out) {
    __shared__ unsigned swmin[4][3], swmax[4][3];
    __shared__ float sm[6];
    __shared__ float tile[4][FEATD];

    const int tid  = threadIdx.x;
    const int gid  = blockIdx.x * SCB + tid;
    const int nth  = gridDim.x * SCB;
    const int wave = tid >> 6;
    const int lane = tid & 63;

    // ---------- phase A: zero counts; per-block minmax partials ----------
    for (int j = gid; j < VOL3; j += nth) counts[j] = 0u;
    if (gid == 0) *ovf_cnt = 0u;
    {
        unsigned kmin[3] = {~0u, ~0u, ~0u};
        unsigned kmax[3] = {0u, 0u, 0u};
        const int nq = n >> 2;
        const float4* p4 = (const float4*)xyz;
        for (int q = gid; q < nq; q += nth) {
            float4 v0 = p4[3 * q], v1 = p4[3 * q + 1], v2 = p4[3 * q + 2];
            float ax[4] = {v0.x, v0.w, v1.z, v2.y};
            float ay[4] = {v0.y, v1.x, v1.w, v2.z};
            float az[4] = {v0.z, v1.y, v2.x, v2.w};
            #pragma unroll
            for (int k = 0; k < 4; k++) {
                if (ax[k] != 0.f && ay[k] != 0.f && az[k] != 0.f) {
                    unsigned kk[3] = {fkey(ax[k]), fkey(ay[k]), fkey(az[k])};
                    #pragma unroll
                    for (int c = 0; c < 3; c++) {
                        kmin[c] = kmin[c] < kk[c] ? kmin[c] : kk[c];
                        kmax[c] = kmax[c] > kk[c] ? kmax[c] : kk[c];
                    }
                }
            }
        }
        for (int i = (nq << 2) + gid; i < n; i += nth) {
            float x = xyz[3 * i], y = xyz[3 * i + 1], z = xyz[3 * i + 2];
            if (x != 0.f && y != 0.f && z != 0.f) {
                unsigned kk[3] = {fkey(x), fkey(y), fkey(z)};
                #pragma unroll
                for (int c = 0; c < 3; c++) {
                    kmin[c] = kmin[c] < kk[c] ? kmin[c] : kk[c];
                    kmax[c] = kmax[c] > kk[c] ? kmax[c] : kk[c];
                }
            }
        }
        #pragma unroll
        for (int o = 32; o; o >>= 1) {
            #pragma unroll
            for (int c = 0; c < 3; c++) {
                unsigned omin = __shfl_xor(kmin[c], o, 64);
                unsigned omax = __shfl_xor(kmax[c], o, 64);
                kmin[c] = kmin[c] < omin ? kmin[c] : omin;
                kmax[c] = kmax[c] > omax ? kmax[c] : omax;
            }
        }
        if (lane == 0) {
            #pragma unroll
            for (int c = 0; c < 3; c++) { swmin[wave][c] = kmin[c]; swmax[wave][c] = kmax[c]; }
        }
        __syncthreads();
        if (tid == 0) {
            #pragma unroll
            for (int c = 0; c < 3; c++) { kmin[c] = swmin[0][c]; kmax[c] = swmax[0][c]; }
            for (int w = 1; w < 4; w++) {
                #pragma unroll
                for (int c = 0; c < 3; c++) {
                    kmin[c] = kmin[c] < swmin[w][c] ? kmin[c] : swmin[w][c];
                    kmax[c] = kmax[c] > swmax[w][c] ? kmax[c] : swmax[w][c];
                }
            }
            #pragma unroll
            for (int c = 0; c < 3; c++) {
                pb[blockIdx.x * 6 + c]     = kmin[c];
                pb[blockIdx.x * 6 + 3 + c] = kmax[c];
            }
        }
    }
    gbar(NBLK);

    // ---------- phase B: redundant partial-reduce; bucket scatter ----------
    {
        unsigned mn[3] = {~0u, ~0u, ~0u}, mx[3] = {0u, 0u, 0u};
        for (int t = tid; t < (int)gridDim.x; t += SCB) {
            #pragma unroll
            for (int c = 0; c < 3; c++) {
                unsigned a = pb[t * 6 + c], b2 = pb[t * 6 + 3 + c];
                mn[c] = mn[c] < a ? mn[c] : a;
                mx[c] = mx[c] > b2 ? mx[c] : b2;
            }
        }
        #pragma unroll
        for (int o = 32; o; o >>= 1) {
            #pragma unroll
            for (int c = 0; c < 3; c++) {
                unsigned omin = __shfl_xor(mn[c], o, 64);
                unsigned omax = __shfl_xor(mx[c], o, 64);
                mn[c] = mn[c] < omin ? mn[c] : omin;
                mx[c] = mx[c] > omax ? mx[c] : omax;
            }
        }
        __syncthreads();
        if (lane == 0) {
            #pragma unroll
            for (int c = 0; c < 3; c++) { swmin[wave][c] = mn[c]; swmax[wave][c] = mx[c]; }
        }
        __syncthreads();
        if (tid == 0) {
            #pragma unroll
            for (int c = 0; c < 3; c++) { mn[c] = swmin[0][c]; mx[c] = swmax[0][c]; }
            for (int w = 1; w < 4; w++) {
                #pragma unroll
                for (int c = 0; c < 3; c++) {
                    mn[c] = mn[c] < swmin[w][c] ? mn[c] : swmin[w][c];
                    mx[c] = mx[c] > swmax[w][c] ? mx[c] : swmax[w][c];
                }
            }
            #pragma unroll
            for (int c = 0; c < 3; c++) { sm[c] = funkey(mn[c]); sm[3 + c] = funkey(mx[c]); }
        }
        __syncthreads();

        const float mnx = sm[0], mny = sm[1], mnz = sm[2];
        const float mxx = sm[3], mxy = sm[4], mxz = sm[5];
        const int nq = (n + 3) >> 2;
        for (int q = gid; q < nq; q += nth) {
            int i0 = q * 4;
            float ax[4], ay[4], az[4];
            int cnt4 = 4;
            if (i0 + 4 <= n) {
                const float4* p4 = (const float4*)(xyz + (size_t)i0 * 3);
                float4 v0 = p4[0], v1 = p4[1], v2 = p4[2];
                ax[0]=v0.x; ax[1]=v0.w; ax[2]=v1.z; ax[3]=v2.y;
                ay[0]=v0.y; ay[1]=v1.x; ay[2]=v1.w; ay[3]=v2.z;
                az[0]=v0.z; az[1]=v1.y; az[2]=v2.x; az[3]=v2.w;
            } else {
                cnt4 = n - i0;
                for (int k = 0; k < cnt4; k++) {
                    ax[k] = xyz[3 * (i0 + k)]; ay[k] = xyz[3 * (i0 + k) + 1]; az[k] = xyz[3 * (i0 + k) + 2];
                }
            }
            #pragma unroll
            for (int k = 0; k < 4; k++) {
                if (k >= cnt4) break;
                if (ax[k] == 0.f || ay[k] == 0.f || az[k] == 0.f) continue;
                // exact op-order of reference: (x-min)/(max-min)*47, f32, trunc
                int cx = (int)((ax[k] - mnx) / (mxx - mnx) * 47.0f);
                int cy = (int)((ay[k] - mny) / (mxy - mny) * 47.0f);
                int cz = (int)((az[k] - mnz) / (mxz - mnz) * 47.0f);
                unsigned cell = (unsigned)((cz * VOL + cy) * VOL + cx);
                unsigned slot = atomicAdd(&counts[cell], 1u);
                if (slot < CAP) {
                    bucket[(size_t)cell * CAP + slot] = (unsigned)(i0 + k);
                } else {
                    unsigned jj = atomicAdd(ovf_cnt, 1u);
                    if (jj < OVCAP) { ovf[2 * jj] = cell; ovf[2 * jj + 1] = (unsigned)(i0 + k); }
                }
            }
        }
    }
    gbar(NBLK);

    // ---------- phase C: accum, grid-stride over 4-cell groups (balanced) ----------
    {
        const int f = lane % FEATD;                 // 0..18
        const int j = lane / FEATD;                 // 0..3 (j==3 idle)
        const bool act = j < 3;
        for (int g = blockIdx.x; g < NGRP; g += NBLK) {
            int cell = g * 4 + wave;
            unsigned cnt = counts[cell];
            unsigned use = cnt < CAP ? cnt : CAP;
            const unsigned* b = bucket + (size_t)cell * CAP;
            float acc = 0.f;
            unsigned idx0 = 0, idx1 = 0;
            bool l0 = act && ((unsigned)j < use);
            bool l1 = act && ((unsigned)(j + 3) < use);
            if (l0) idx0 = b[j];
            if (l1) idx1 = b[j + 3];
            unsigned k = 0;
            while (k < use) {
                unsigned nk = k + 6;
                bool n0 = act && (nk + j < use);
                bool n1 = act && (nk + j + 3 < use);
                unsigned nidx0 = 0, nidx1 = 0;
                if (n0) nidx0 = b[nk + j];
                if (n1) nidx1 = b[nk + j + 3];
                if (l0) acc += feat[(size_t)idx0 * FEATD + f];
                if (l1) acc += feat[(size_t)idx1 * FEATD + f];
                k = nk; idx0 = nidx0; idx1 = nidx1; l0 = n0; l1 = n1;
            }
            if (cnt > CAP) {   // cold overflow merge (never taken for this data)
                unsigned no = *ovf_cnt; if (no > OVCAP) no = OVCAP;
                if (lane < FEATD) {
                    for (unsigned ii = 0; ii < no; ii++)
                        if (ovf[2 * ii] == (unsigned)cell)
                            acc += feat[(size_t)ovf[2 * ii + 1] * FEATD + f];
                }
            }
            float a1 = __shfl(acc, lane + FEATD, 64);
            float a2 = __shfl(acc, lane + 2 * FEATD, 64);
            if (lane < FEATD) tile[wave][lane] = acc + a1 + a2;
            __syncthreads();
            if (tid < 4 * FEATD) {
                int ff = tid >> 2, c = tid & 3;
                center[(size_t)ff * VOL3 + g * 4 + c] = tile[c][ff];
            }
            __syncthreads();
        }
    }
    gbar(NBLK);

    // ---------- phase D: 3x3x3 box conv (rolling z), grid-stride ----------
    {
        const int NT = FEATD * (VOL / ZK) * VOL * VOL;
        for (int idx = gid; idx < NT; idx += nth) {
            int x = idx % VOL;
            int t = idx / VOL;
            int y = t % VOL;  t /= VOL;
            int zb = t % (VOL / ZK);
            int f = t / (VOL / ZK);
            const float* cf = center + (size_t)f * VOL3;
            int ylo = (y > 0) ? y - 1 : 0, yhi = (y < VOL - 1) ? y + 1 : VOL - 1;
            int xlo = (x > 0) ? x - 1 : 0, xhi = (x < VOL - 1) ? x + 1 : VOL - 1;
            auto psum = [&](int zz) -> float {
                if ((unsigned)zz >= (unsigned)VOL) return 0.f;
                float s = 0.f;
                for (int yy = ylo; yy <= yhi; yy++) {
                    const float* row = cf + (zz * VOL + yy) * VOL;
                    for (int xx = xlo; xx <= xhi; xx++) s += row[xx];
                }
                return s;
            };
            int z0 = zb * ZK;
            float Pm = psum(z0 - 1), Pc = psum(z0);
            #pragma unroll
            for (int k = 0; k < ZK; k++) {
                float Pn = psum(z0 + k + 1);
                out[(((size_t)f * VOL + (z0 + k)) * VOL + y) * VOL + x] = Pm + Pc + Pn;
                Pm = Pc; Pc = Pn;
            }
        }
    }
}

// ================= fallback: r8's 4-dispatch pipeline =================
__global__ __launch_bounds__(1024) void vox_minmax_p(const float* __restrict__ xyz,
                                                     int n, unsigned* __restrict__ pb,
                                                     unsigned* __restrict__ counts,
                                                     unsigned* __restrict__ ovf_cnt) {
    int gid = blockIdx.x * blockDim.x + threadIdx.x;
    for (int j = gid; j < VOL3; j += gridDim.x * blockDim.x) counts[j] = 0u;
    if (gid == 0) *ovf_cnt = 0u;
    __shared__ unsigned smin[16][3], smax[16][3];
    unsigned kmin[3] = {~0u, ~0u, ~0u};
    unsigned kmax[3] = {0u, 0u, 0u};
    const int nq = n >> 2;
    const float4* p4 = (const float4*)xyz;
    for (int q = gid; q < nq; q += gridDim.x * blockDim.x) {
        float4 v0 = p4[3 * q], v1 = p4[3 * q + 1], v2 = p4[3 * q + 2];
        float ax[4] = {v0.x, v0.w, v1.z, v2.y};
        float ay[4] = {v0.y, v1.x, v1.w, v2.z};
        float az[4] = {v0.z, v1.y, v2.x, v2.w};
        #pragma unroll
        for (int k = 0; k < 4; k++) {
            if (ax[k] != 0.f && ay[k] != 0.f && az[k] != 0.f) {
                unsigned kk[3] = {fkey(ax[k]), fkey(ay[k]), fkey(az[k])};
                #pragma unroll
                for (int c = 0; c < 3; c++) {
                    kmin[c] = kmin[c] < kk[c] ? kmin[c] : kk[c];
                    kmax[c] = kmax[c] > kk[c] ? kmax[c] : kk[c];
                }
            }
        }
    }
    for (int i = (nq << 2) + gid; i < n; i += gridDim.x * blockDim.x) {
        float x = xyz[3 * i], y = xyz[3 * i + 1], z = xyz[3 * i + 2];
        if (x != 0.f && y != 0.f && z != 0.f) {
            unsigned kk[3] = {fkey(x), fkey(y), fkey(z)};
            #pragma unroll
            for (int c = 0; c < 3; c++) {
                kmin[c] = kmin[c] < kk[c] ? kmin[c] : kk[c];
                kmax[c] = kmax[c] > kk[c] ? kmax[c] : kk[c];
            }
        }
    }
    #pragma unroll
    for (int o = 32; o; o >>= 1) {
        #pragma unroll
        for (int c = 0; c < 3; c++) {
            unsigned omin = __shfl_xor(kmin[c], o, 64);
            unsigned omax = __shfl_xor(kmax[c], o, 64);
            kmin[c] = kmin[c] < omin ? kmin[c] : omin;
            kmax[c] = kmax[c] > omax ? kmax[c] : omax;
        }
    }
    int wave = threadIdx.x >> 6;
    if ((threadIdx.x & 63) == 0) {
        #pragma unroll
        for (int c = 0; c < 3; c++) { smin[wave][c] = kmin[c]; smax[wave][c] = kmax[c]; }
    }
    __syncthreads();
    if (threadIdx.x == 0) {
        int nw = blockDim.x >> 6;
        #pragma unroll
        for (int c = 0; c < 3; c++) { kmin[c] = smin[0][c]; kmax[c] = smax[0][c]; }
        for (int w = 1; w < nw; w++) {
            #pragma unroll
            for (int c = 0; c < 3; c++) {
                kmin[c] = kmin[c] < smin[w][c] ? kmin[c] : smin[w][c];
                kmax[c] = kmax[c] > smax[w][c] ? kmax[c] : smax[w][c];
            }
        }
        #pragma unroll
        for (int c = 0; c < 3; c++) {
            pb[blockIdx.x * 6 + c]     = kmin[c];
            pb[blockIdx.x * 6 + 3 + c] = kmax[c];
        }
    }
}

__device__ __forceinline__ void reduce_keys64(const unsigned* __restrict__ pb,
                                              float* __restrict__ sm) {
    if (threadIdx.x < 64) {
        unsigned mn[3], mx[3];
        int t = threadIdx.x;
        #pragma unroll
        for (int c = 0; c < 3; c++) {
            mn[c] = pb[t * 6 + c];
            mx[c] = pb[t * 6 + 3 + c];
        }
        #pragma unroll
        for (int o = 32; o; o >>= 1) {
            #pragma unroll
            for (int c = 0; c < 3; c++) {
                unsigned omin = __shfl_xor(mn[c], o, 64);
                unsigned omax = __shfl_xor(mx[c], o, 64);
                mn[c] = mn[c] < omin ? mn[c] : omin;
                mx[c] = mx[c] > omax ? mx[c] : omax;
            }
        }
        if (t == 0) {
            #pragma unroll
            for (int c = 0; c < 3; c++) { sm[c] = funkey(mn[c]); sm[3 + c] = funkey(mx[c]); }
        }
    }
    __syncthreads();
}

__global__ __launch_bounds__(SCB) void vox_scatter(const float* __restrict__ xyz, int n,
                                                   const unsigned* __restrict__ pb,
                                                   unsigned* __restrict__ counts,
                                                   unsigned* __restrict__ bucket,
                                                   unsigned* __restrict__ ovf,
                                                   unsigned* __restrict__ ovf_cnt) {
    __shared__ float sm[6];
    reduce_keys64(pb, sm);
    const float mnx = sm[0], mny = sm[1], mnz = sm[2];
    const float mxx = sm[3], mxy = sm[4], mxz = sm[5];
    int q = blockIdx.x * blockDim.x + threadIdx.x;
    int i0 = q * 4;
    if (i0 >= n) return;
    float ax[4], ay[4], az[4];
    int cnt4 = 4;
    if (i0 + 4 <= n) {
        const float4* p4 = (const float4*)(xyz + (size_t)i0 * 3);
        float4 v0 = p4[0], v1 = p4[1], v2 = p4[2];
        ax[0]=v0.x; ax[1]=v0.w; ax[2]=v1.z; ax[3]=v2.y;
        ay[0]=v0.y; ay[1]=v1.x; ay[2]=v1.w; ay[3]=v2.z;
        az[0]=v0.z; az[1]=v1.y; az[2]=v2.x; az[3]=v2.w;
    } else {
        cnt4 = n - i0;
        for (int k = 0; k < cnt4; k++) {
            ax[k] = xyz[3 * (i0 + k)]; ay[k] = xyz[3 * (i0 + k) + 1]; az[k] = xyz[3 * (i0 + k) + 2];
        }
    }
    #pragma unroll
    for (int k = 0; k < 4; k++) {
        if (k >= cnt4) break;
        if (ax[k] == 0.f || ay[k] == 0.f || az[k] == 0.f) continue;
        int cx = (int)((ax[k] - mnx) / (mxx - mnx) * 47.0f);
        int cy = (int)((ay[k] - mny) / (mxy - mny) * 47.0f);
        int cz = (int)((az[k] - mnz) / (mxz - mnz) * 47.0f);
        unsigned cell = (unsigned)((cz * VOL + cy) * VOL + cx);
        unsigned slot = atomicAdd(&counts[cell], 1u);
        if (slot < CAP) {
            bucket[(size_t)cell * CAP + slot] = (unsigned)(i0 + k);
        } else {
            unsigned j = atomicAdd(ovf_cnt, 1u);
            if (j < OVCAP) { ovf[2 * j] = cell; ovf[2 * j + 1] = (unsigned)(i0 + k); }
        }
    }
}

__global__ __launch_bounds__(256) void vox_accum(const unsigned* __restrict__ bucket,
                                                 const unsigned* __restrict__ counts,
                                                 const unsigned* __restrict__ ovf,
                                                 const unsigned* __restrict__ ovf_cnt,
                                                 const float* __restrict__ feat,
                                                 float* __restrict__ center) {
    __shared__ float tile[4][FEATD];
    const int wave = threadIdx.x >> 6;
    const int lane = threadIdx.x & 63;
    const int cell = blockIdx.x * 4 + wave;
    const int f = lane % FEATD;
    const int j = lane / FEATD;
    const bool act = j < 3;
    unsigned cnt = counts[cell];
    unsigned use = cnt < CAP ? cnt : CAP;
    const unsigned* b = bucket + (size_t)cell * CAP;
    float acc = 0.f;
    unsigned idx0 = 0, idx1 = 0;
    bool l0 = act && ((unsigned)j < use);
    bool l1 = act && ((unsigned)(j + 3) < use);
    if (l0) idx0 = b[j];
    if (l1) idx1 = b[j + 3];
    unsigned k = 0;
    while (k < use) {
        unsigned nk = k + 6;
        bool n0 = act && (nk + j < use);
        bool n1 = act && (nk + j + 3 < use);
        unsigned nidx0 = 0, nidx1 = 0;
        if (n0) nidx0 = b[nk + j];
        if (n1) nidx1 = b[nk + j + 3];
        if (l0) acc += feat[(size_t)idx0 * FEATD + f];
        if (l1) acc += feat[(size_t)idx1 * FEATD + f];
        k = nk; idx0 = nidx0; idx1 = nidx1; l0 = n0; l1 = n1;
    }
    if (cnt > CAP) {
        unsigned no = *ovf_cnt; if (no > OVCAP) no = OVCAP;
        if (lane < FEATD) {
            for (unsigned i = 0; i < no; i++)
                if (ovf[2 * i] == (unsigned)cell)
                    acc += feat[(size_t)ovf[2 * i + 1] * FEATD + f];
        }
    }
    float a1 = __shfl(acc, lane + FEATD, 64);
    float a2 = __shfl(acc, lane + 2 * FEATD, 64);
    if (lane < FEATD) tile[wave][lane] = acc + a1 + a2;
    __syncthreads();
    int t = threadIdx.x;
    if (t < 4 * FEATD) {
        int ff = t >> 2, c = t & 3;
        center[(size_t)ff * VOL3 + blockIdx.x * 4 + c] = tile[c][ff];
    }
}

__global__ void vox_conv(const float* __restrict__ center, float* __restrict__ out) {
    int idx = blockIdx.x * blockDim.x + threadIdx.x;
    const int NT = FEATD * (VOL / ZK) * VOL * VOL;
    if (idx >= NT) return;
    int x = idx % VOL;
    int t = idx / VOL;
    int y = t % VOL;  t /= VOL;
    int zb = t % (VOL / ZK);
    int f = t / (VOL / ZK);
    const float* cf = center + (size_t)f * VOL3;
    int ylo = (y > 0) ? y - 1 : 0, yhi = (y < VOL - 1) ? y + 1 : VOL - 1;
    int xlo = (x > 0) ? x - 1 : 0, xhi = (x < VOL - 1) ? x + 1 : VOL - 1;
    auto psum = [&](int zz) -> float {
        if ((unsigned)zz >= (unsigned)VOL) return 0.f;
        float s = 0.f;
        for (int yy = ylo; yy <= yhi; yy++) {
            const float* row = cf + (zz * VOL + yy) * VOL;
            for (int xx = xlo; xx <= xhi; xx++) s += row[xx];
        }
        return s;
    };
    int z0 = zb * ZK;
    float Pm = psum(z0 - 1), Pc = psum(z0);
    #pragma unroll
    for (int k = 0; k < ZK; k++) {
        float Pn = psum(z0 + k + 1);
        out[(((size_t)f * VOL + (z0 + k)) * VOL + y) * VOL + x] = Pm + Pc + Pn;
        Pm = Pc; Pc = Pn;
    }
}

extern "C" void kernel_launch(void* const* d_in, const int* in_sizes, int n_in,
                              void* d_out, int out_size, void* d_ws, size_t ws_size,
                              hipStream_t stream) {
    const float* xyz  = (const float*)d_in[0];
    const float* feat = (const float*)d_in[1];
    float* out = (float*)d_out;
    int n = in_sizes[0] / 3;

    char* w = (char*)d_ws;
    unsigned* pb      = (unsigned*)w;                        // NBLK*6 u32 = 24 KB
    size_t o1 = (size_t)NBLK * 6 * 4;                        // 24576
    unsigned* ovf_cnt = (unsigned*)(w + o1);                 // 4 B (pad to 256)
    size_t o2 = o1 + 256;                                    // 24832
    unsigned* counts  = (unsigned*)(w + o2);                 // VOL3*4 = 442368
    size_t o3 = o2 + (size_t)VOL3 * 4;                       // 467200
    unsigned* bucket  = (unsigned*)(w + o3);                 // VOL3*CAP*4 = 56.6 MB
    size_t o4 = o3 + (size_t)VOL3 * CAP * 4;
    float* center     = (float*)(w + o4);                    // FEATD*VOL3*4 = 8.4 MB
    size_t o5 = o4 + (size_t)FEATD * VOL3 * 4;
    unsigned* ovf     = (unsigned*)(w + o5);                 // 2*OVCAP*4 = 64 KB
    size_t need = o5 + (size_t)2 * OVCAP * 4;

    if (ws_size < need) return;  // ws is ~256MB in this harness; never taken

    void* args[] = {(void*)&xyz, (void*)&feat, (void*)&n, (void*)&pb,
                    (void*)&counts, (void*)&ovf_cnt, (void*)&bucket,
                    (void*)&ovf, (void*)&center, (void*)&out};
    hipError_t e = hipLaunchCooperativeKernel((const void*)vox_mega, dim3(NBLK),
                                              dim3(SCB), args, 0, stream);
    if (e != hipSuccess) {
        // fallback: proven 4-dispatch pipeline (r8, 62 us)
        int nq = (n + 3) / 4;
        vox_minmax_p<<<64, 1024, 0, stream>>>(xyz, n, pb, counts, ovf_cnt);
        vox_scatter<<<(nq + SCB - 1) / SCB, SCB, 0, stream>>>(xyz, n, pb, counts, bucket, ovf, ovf_cnt);
        vox_accum<<<VOL3 / 4, 256, 0, stream>>>(bucket, counts, ovf, ovf_cnt, feat, center);
        const int nconv = FEATD * (VOL / ZK) * VOL * VOL;
        vox_conv<<<(nconv + SCB - 1) / SCB, SCB, 0, stream>>>(center, out);
    }
}

// Round 11
// 53.234 us; speedup vs baseline: 11.8797x; 11.8797x over previous
//
#include <hip/hip_runtime.h>

// Voxelizer3D: out[f][z][y][x] = sum over masked atoms (all coords != 0) whose
// center cell is within Chebyshev distance 1 of (x,y,z), of feat[a][f].
// v11: proven r8 4-dispatch bucket pipeline (62us), with a vectorized conv:
// each thread computes a 4x4 (x,z) output tile via float4 row loads + rolling-z.
// (v9/v10 lesson: grid-wide sync on MI355X costs ~100+us -> mega-kernel dead end.)

constexpr int VOL   = 48;
constexpr int FEATD = 19;
constexpr int VOL3  = VOL * VOL * VOL;      // 110592
constexpr int CAP   = 128;                  // bucket capacity per cell
constexpr int OVCAP = 8192;                 // overflow list capacity (cold)
constexpr int NMB   = 64;                   // minmax partial blocks
constexpr int SCB   = 256;

__device__ __forceinline__ unsigned fkey(float f) {
    unsigned u = __float_as_uint(f);
    return (u & 0x80000000u) ? ~u : (u | 0x80000000u);
}
__device__ __forceinline__ float funkey(unsigned k) {
    unsigned u = (k & 0x80000000u) ? (k & 0x7fffffffu) : ~k;
    return __uint_as_float(u);
}

// ---- K1: per-block min/max partials; zero counts + ovf counter ----
__global__ __launch_bounds__(1024) void vox_minmax_p(const float* __restrict__ xyz,
                                                     int n, unsigned* __restrict__ pb,
                                                     unsigned* __restrict__ counts,
                                                     unsigned* __restrict__ ovf_cnt) {
    int gid = blockIdx.x * blockDim.x + threadIdx.x;
    for (int j = gid; j < VOL3; j += gridDim.x * blockDim.x) counts[j] = 0u;
    if (gid == 0) *ovf_cnt = 0u;
    __shared__ unsigned smin[16][3], smax[16][3];
    unsigned kmin[3] = {~0u, ~0u, ~0u};
    unsigned kmax[3] = {0u, 0u, 0u};
    const int nq = n >> 2;
    const float4* p4 = (const float4*)xyz;
    for (int q = gid; q < nq; q += gridDim.x * blockDim.x) {
        float4 v0 = p4[3 * q], v1 = p4[3 * q + 1], v2 = p4[3 * q + 2];
        float ax[4] = {v0.x, v0.w, v1.z, v2.y};
        float ay[4] = {v0.y, v1.x, v1.w, v2.z};
        float az[4] = {v0.z, v1.y, v2.x, v2.w};
        #pragma unroll
        for (int k = 0; k < 4; k++) {
            if (ax[k] != 0.f && ay[k] != 0.f && az[k] != 0.f) {
                unsigned kk[3] = {fkey(ax[k]), fkey(ay[k]), fkey(az[k])};
                #pragma unroll
                for (int c = 0; c < 3; c++) {
                    kmin[c] = kmin[c] < kk[c] ? kmin[c] : kk[c];
                    kmax[c] = kmax[c] > kk[c] ? kmax[c] : kk[c];
                }
            }
        }
    }
    for (int i = (nq << 2) + gid; i < n; i += gridDim.x * blockDim.x) {
        float x = xyz[3 * i], y = xyz[3 * i + 1], z = xyz[3 * i + 2];
        if (x != 0.f && y != 0.f && z != 0.f) {
            unsigned kk[3] = {fkey(x), fkey(y), fkey(z)};
            #pragma unroll
            for (int c = 0; c < 3; c++) {
                kmin[c] = kmin[c] < kk[c] ? kmin[c] : kk[c];
                kmax[c] = kmax[c] > kk[c] ? kmax[c] : kk[c];
            }
        }
    }
    #pragma unroll
    for (int o = 32; o; o >>= 1) {
        #pragma unroll
        for (int c = 0; c < 3; c++) {
            unsigned omin = __shfl_xor(kmin[c], o, 64);
            unsigned omax = __shfl_xor(kmax[c], o, 64);
            kmin[c] = kmin[c] < omin ? kmin[c] : omin;
            kmax[c] = kmax[c] > omax ? kmax[c] : omax;
        }
    }
    int wave = threadIdx.x >> 6;
    if ((threadIdx.x & 63) == 0) {
        #pragma unroll
        for (int c = 0; c < 3; c++) { smin[wave][c] = kmin[c]; smax[wave][c] = kmax[c]; }
    }
    __syncthreads();
    if (threadIdx.x == 0) {
        int nw = blockDim.x >> 6;
        #pragma unroll
        for (int c = 0; c < 3; c++) { kmin[c] = smin[0][c]; kmax[c] = smax[0][c]; }
        for (int w = 1; w < nw; w++) {
            #pragma unroll
            for (int c = 0; c < 3; c++) {
                kmin[c] = kmin[c] < smin[w][c] ? kmin[c] : smin[w][c];
                kmax[c] = kmax[c] > smax[w][c] ? kmax[c] : smax[w][c];
            }
        }
        #pragma unroll
        for (int c = 0; c < 3; c++) {
            pb[blockIdx.x * 6 + c]     = kmin[c];
            pb[blockIdx.x * 6 + 3 + c] = kmax[c];
        }
    }
}

// reduce the NMB partials -> 6 floats, broadcast via LDS
__device__ __forceinline__ void reduce_keys64(const unsigned* __restrict__ pb,
                                              float* __restrict__ sm) {
    if (threadIdx.x < 64) {
        unsigned mn[3], mx[3];
        int t = threadIdx.x;
        #pragma unroll
        for (int c = 0; c < 3; c++) {
            mn[c] = pb[t * 6 + c];
            mx[c] = pb[t * 6 + 3 + c];
        }
        #pragma unroll
        for (int o = 32; o; o >>= 1) {
            #pragma unroll
            for (int c = 0; c < 3; c++) {
                unsigned omin = __shfl_xor(mn[c], o, 64);
                unsigned omax = __shfl_xor(mx[c], o, 64);
                mn[c] = mn[c] < omin ? mn[c] : omin;
                mx[c] = mx[c] > omax ? mx[c] : omax;
            }
        }
        if (t == 0) {
            #pragma unroll
            for (int c = 0; c < 3; c++) { sm[c] = funkey(mn[c]); sm[3 + c] = funkey(mx[c]); }
        }
    }
    __syncthreads();
}

// ---- K2: fused cell-compute + count + bucket-place (4 atoms/thread) ----
__global__ __launch_bounds__(SCB) void vox_scatter(const float* __restrict__ xyz, int n,
                                                   const unsigned* __restrict__ pb,
                                                   unsigned* __restrict__ counts,
                                                   unsigned* __restrict__ bucket,
                                                   unsigned* __restrict__ ovf,
                                                   unsigned* __restrict__ ovf_cnt) {
    __shared__ float sm[6];
    reduce_keys64(pb, sm);
    const float mnx = sm[0], mny = sm[1], mnz = sm[2];
    const float mxx = sm[3], mxy = sm[4], mxz = sm[5];
    int q = blockIdx.x * blockDim.x + threadIdx.x;
    int i0 = q * 4;
    if (i0 >= n) return;
    float ax[4], ay[4], az[4];
    int cnt4 = 4;
    if (i0 + 4 <= n) {
        const float4* p4 = (const float4*)(xyz + (size_t)i0 * 3);
        float4 v0 = p4[0], v1 = p4[1], v2 = p4[2];
        ax[0]=v0.x; ax[1]=v0.w; ax[2]=v1.z; ax[3]=v2.y;
        ay[0]=v0.y; ay[1]=v1.x; ay[2]=v1.w; ay[3]=v2.z;
        az[0]=v0.z; az[1]=v1.y; az[2]=v2.x; az[3]=v2.w;
    } else {
        cnt4 = n - i0;
        for (int k = 0; k < cnt4; k++) {
            ax[k] = xyz[3 * (i0 + k)]; ay[k] = xyz[3 * (i0 + k) + 1]; az[k] = xyz[3 * (i0 + k) + 2];
        }
    }
    #pragma unroll
    for (int k = 0; k < 4; k++) {
        if (k >= cnt4) break;
        if (ax[k] == 0.f || ay[k] == 0.f || az[k] == 0.f) continue;
        // exact op-order of reference: (x - min) / (max - min) * 47, f32, trunc
        int cx = (int)((ax[k] - mnx) / (mxx - mnx) * 47.0f);
        int cy = (int)((ay[k] - mny) / (mxy - mny) * 47.0f);
        int cz = (int)((az[k] - mnz) / (mxz - mnz) * 47.0f);
        unsigned cell = (unsigned)((cz * VOL + cy) * VOL + cx);
        unsigned slot = atomicAdd(&counts[cell], 1u);
        if (slot < CAP) {
            bucket[(size_t)cell * CAP + slot] = (unsigned)(i0 + k);
        } else {
            unsigned j = atomicAdd(ovf_cnt, 1u);
            if (j < OVCAP) { ovf[2 * j] = cell; ovf[2 * j + 1] = (unsigned)(i0 + k); }
        }
    }
}

// ---- K3: accum, one WAVE per cell; lane = f + 19*j -> coalesced row reads ----
__global__ __launch_bounds__(256) void vox_accum(const unsigned* __restrict__ bucket,
                                                 const unsigned* __restrict__ counts,
                                                 const unsigned* __restrict__ ovf,
                                                 const unsigned* __restrict__ ovf_cnt,
                                                 const float* __restrict__ feat,
                                                 float* __restrict__ center) {
    __shared__ float tile[4][FEATD];
    const int wave = threadIdx.x >> 6;
    const int lane = threadIdx.x & 63;
    const int cell = blockIdx.x * 4 + wave;
    const int f = lane % FEATD;
    const int j = lane / FEATD;
    const bool act = j < 3;
    unsigned cnt = counts[cell];
    unsigned use = cnt < CAP ? cnt : CAP;
    const unsigned* b = bucket + (size_t)cell * CAP;
    float acc = 0.f;
    unsigned idx0 = 0, idx1 = 0;
    bool l0 = act && ((unsigned)j < use);
    bool l1 = act && ((unsigned)(j + 3) < use);
    if (l0) idx0 = b[j];
    if (l1) idx1 = b[j + 3];
    unsigned k = 0;
    while (k < use) {
        unsigned nk = k + 6;
        bool n0 = act && (nk + j < use);
        bool n1 = act && (nk + j + 3 < use);
        unsigned nidx0 = 0, nidx1 = 0;
        if (n0) nidx0 = b[nk + j];
        if (n1) nidx1 = b[nk + j + 3];
        if (l0) acc += feat[(size_t)idx0 * FEATD + f];
        if (l1) acc += feat[(size_t)idx1 * FEATD + f];
        k = nk; idx0 = nidx0; idx1 = nidx1; l0 = n0; l1 = n1;
    }
    if (cnt > CAP) {
        unsigned no = *ovf_cnt; if (no > OVCAP) no = OVCAP;
        if (lane < FEATD) {
            for (unsigned i = 0; i < no; i++)
                if (ovf[2 * i] == (unsigned)cell)
                    acc += feat[(size_t)ovf[2 * i + 1] * FEATD + f];
        }
    }
    float a1 = __shfl(acc, lane + FEATD, 64);
    float a2 = __shfl(acc, lane + 2 * FEATD, 64);
    if (lane < FEATD) tile[wave][lane] = acc + a1 + a2;
    __syncthreads();
    int t = threadIdx.x;
    if (t < 4 * FEATD) {
        int ff = t >> 2, c = t & 3;
        center[(size_t)ff * VOL3 + blockIdx.x * 4 + c] = tile[c][ff];
    }
}

// ---- K4: 3x3x3 box conv; thread computes a 4x4 (x,z) tile via float4 rows ----
constexpr int XQ = VOL / 4;     // 12 x-quads
constexpr int CZB = VOL / 4;    // 12 z-blocks (4 z per thread)
constexpr int NCONV2 = FEATD * CZB * VOL * XQ;   // 131328 threads

__global__ __launch_bounds__(SCB) void vox_conv2(const float* __restrict__ center,
                                                 float* __restrict__ out) {
    int idx = blockIdx.x * blockDim.x + threadIdx.x;
    if (idx >= NCONV2) return;
    int xq = idx % XQ;
    int t = idx / XQ;
    int y = t % VOL;  t /= VOL;
    int zb = t % CZB;
    int f = t / CZB;
    const int x0 = xq * 4;
    const float* cf = center + (size_t)f * VOL3;

    const int ylo = (y > 0) ? y - 1 : 0, yhi = (y < VOL - 1) ? y + 1 : VOL - 1;

    // quad of 3-tap x-sums for one row
    auto rowsum4 = [&](const float* row) -> float4 {
        float4 a = *(const float4*)(row + x0);
        float m = (x0 > 0) ? row[x0 - 1] : 0.f;
        float p = (x0 + 4 < VOL) ? row[x0 + 4] : 0.f;
        return make_float4(m + a.x + a.y,
                           a.x + a.y + a.z,
                           a.y + a.z + a.w,
                           a.z + a.w + p);
    };
    // plane sum: rows y-1..y+1 of plane zz
    auto psum = [&](int zz) -> float4 {
        float4 s = make_float4(0.f, 0.f, 0.f, 0.f);
        if ((unsigned)zz >= (unsigned)VOL) return s;
        for (int yy = ylo; yy <= yhi; yy++) {
            float4 r = rowsum4(cf + (zz * VOL + yy) * VOL);
            s.x += r.x; s.y += r.y; s.z += r.z; s.w += r.w;
        }
        return s;
    };

    const int z0 = zb * 4;
    float4 Pm = psum(z0 - 1), Pc = psum(z0);
    #pragma unroll
    for (int k = 0; k < 4; k++) {
        float4 Pn = psum(z0 + k + 1);
        float4 o = make_float4(Pm.x + Pc.x + Pn.x, Pm.y + Pc.y + Pn.y,
                               Pm.z + Pc.z + Pn.z, Pm.w + Pc.w + Pn.w);
        *(float4*)(out + (((size_t)f * VOL + (z0 + k)) * VOL + y) * VOL + x0) = o;
        Pm = Pc; Pc = Pn;
    }
}

extern "C" void kernel_launch(void* const* d_in, const int* in_sizes, int n_in,
                              void* d_out, int out_size, void* d_ws, size_t ws_size,
                              hipStream_t stream) {
    const float* xyz  = (const float*)d_in[0];
    const float* feat = (const float*)d_in[1];
    float* out = (float*)d_out;
    int n = in_sizes[0] / 3;

    char* w = (char*)d_ws;
    unsigned* pb      = (unsigned*)w;                        // NMB*6 u32 = 1536 B
    unsigned* ovf_cnt = (unsigned*)(w + 1536);               // 4 B (pad to 2048)
    unsigned* counts  = (unsigned*)(w + 2048);               // VOL3*4 = 442368
    size_t o3 = 2048 + (size_t)VOL3 * 4;                     // 444416 (256-aligned)
    unsigned* bucket  = (unsigned*)(w + o3);                 // VOL3*CAP*4 = 56.6 MB
    size_t o4 = o3 + (size_t)VOL3 * CAP * 4;
    float* center     = (float*)(w + o4);                    // FEATD*VOL3*4 = 8.4 MB
    size_t o5 = o4 + (size_t)FEATD * VOL3 * 4;
    unsigned* ovf     = (unsigned*)(w + o5);                 // 2*OVCAP*4 = 64 KB
    size_t need = o5 + (size_t)2 * OVCAP * 4;

    if (ws_size < need) return;   // harness ws is ~256MB; never taken

    int nq = (n + 3) / 4;
    vox_minmax_p<<<NMB, 1024, 0, stream>>>(xyz, n, pb, counts, ovf_cnt);
    vox_scatter<<<(nq + SCB - 1) / SCB, SCB, 0, stream>>>(xyz, n, pb, counts, bucket, ovf, ovf_cnt);
    vox_accum<<<VOL3 / 4, 256, 0, stream>>>(bucket, counts, ovf, ovf_cnt, feat, center);
    vox_conv2<<<(NCONV2 + SCB - 1) / SCB, SCB, 0, stream>>>(center, out);
}